// Round 2
// baseline (355.896 us; speedup 1.0000x reference)
//
#include <hip/hip_runtime.h>
#include <hip/hip_bf16.h>
#include <cstdint>

// Problem shape (Transducer joint network):
//   enc (4,160,640) fp32, dec (4,80,640) fp32, W1 (1280,640), b1 (640),
//   W2 (640,1024), b2 (1024).  out = (4,160,80,1024) fp32 = 52.4M floats.
#define B_    4
#define T_    160
#define U_    80
#define D_    640      // De = Dd = inner
#define V_    1024
#define BT_   640      // B*T
#define BU_   320      // B*U
#define M_    51200    // B*T*U

typedef __bf16 bf16x8 __attribute__((ext_vector_type(8)));
typedef float floatx4 __attribute__((ext_vector_type(4)));

__device__ __forceinline__ void g2l16(const void* g, void* l) {
    __builtin_amdgcn_global_load_lds((const __attribute__((address_space(1))) void*)g,
                                     (__attribute__((address_space(3))) void*)l,
                                     16, 0, 0);
}

__device__ __forceinline__ float fast_tanh(float x) {
    float e = __builtin_amdgcn_exp2f(x * 2.8853900817779268f); // 2*log2(e)
    return 1.0f - 2.0f * __builtin_amdgcn_rcpf(e + 1.0f);
}

// ---------------------------------------------------------------------------
// Kernel 1: fp32 projections. 64x64 C-tiles, 4x4 outputs/thread, BK=32.
// Per kk: 4 scalar As reads (4 addrs -> 2 banks x2 = free 2-way) +
// 1 float4 Ws read + 16 FMA  (was 4 reads : 4 FMA at 32x32/2x2).
// ---------------------------------------------------------------------------
__global__ __launch_bounds__(256) void proj_kernel(
    const float* __restrict__ enc, const float* __restrict__ dec,
    const float* __restrict__ W1,
    float* __restrict__ encp, float* __restrict__ decp) {
    __shared__ float As[64][36];   // 9.2 KB; row=144B keeps 16B-aligned float4 staging
    __shared__ float Ws[32][68];   // 8.7 KB; row=272B, 16B-aligned float4 reads

    const int rt = blockIdx.y;     // 0..14 (10 enc row-tiles, 5 dec row-tiles)
    const int ct = blockIdx.x;     // 0..9  (640 cols / 64)
    const float* Asrc; const float* Wsrc; float* Cdst;
    if (rt < 10) { Asrc = enc + (size_t)rt * 64 * D_;        Wsrc = W1;           Cdst = encp + (size_t)rt * 64 * D_; }
    else         { Asrc = dec + (size_t)(rt - 10) * 64 * D_; Wsrc = W1 + D_ * D_; Cdst = decp + (size_t)(rt - 10) * 64 * D_; }

    const int tid = threadIdx.x;
    const int ar = tid >> 2,  ac = (tid & 3) * 8;   // A staging: 8 floats/thread
    const int wr2 = tid >> 3, wc2 = (tid & 7) * 8;  // W staging: 8 floats/thread
    const int tr = tid >> 4,  tc = tid & 15;        // compute: 4x4 per thread

    float acc[4][4] = {};
    for (int k0 = 0; k0 < D_; k0 += 32) {
        __syncthreads();
        *(floatx4*)&As[ar][ac]       = *(const floatx4*)&Asrc[(size_t)ar * D_ + k0 + ac];
        *(floatx4*)&As[ar][ac + 4]   = *(const floatx4*)&Asrc[(size_t)ar * D_ + k0 + ac + 4];
        *(floatx4*)&Ws[wr2][wc2]     = *(const floatx4*)&Wsrc[(size_t)(k0 + wr2) * D_ + ct * 64 + wc2];
        *(floatx4*)&Ws[wr2][wc2 + 4] = *(const floatx4*)&Wsrc[(size_t)(k0 + wr2) * D_ + ct * 64 + wc2 + 4];
        __syncthreads();
#pragma unroll
        for (int kk = 0; kk < 32; kk++) {
            floatx4 w = *(const floatx4*)&Ws[kk][tc * 4];
            float a0 = As[tr * 4 + 0][kk], a1 = As[tr * 4 + 1][kk];
            float a2 = As[tr * 4 + 2][kk], a3 = As[tr * 4 + 3][kk];
#pragma unroll
            for (int j = 0; j < 4; j++) {
                acc[0][j] += a0 * w[j]; acc[1][j] += a1 * w[j];
                acc[2][j] += a2 * w[j]; acc[3][j] += a3 * w[j];
            }
        }
    }
#pragma unroll
    for (int i = 0; i < 4; i++) {
        floatx4 v = { acc[i][0], acc[i][1], acc[i][2], acc[i][3] };
        *(floatx4*)&Cdst[(size_t)(tr * 4 + i) * D_ + ct * 64 + tc * 4] = v;
    }
}

// ---------------------------------------------------------------------------
// Kernel 2: W2 (640x1024 fp32, KxN) -> W2t (1024x640 bf16, NxK). Unchanged.
// ---------------------------------------------------------------------------
__global__ __launch_bounds__(256) void w2t_kernel(
    const float* __restrict__ W2, __bf16* __restrict__ W2t) {
    __shared__ __bf16 tile[32][33];
    const int vt = blockIdx.x;
    const int kt = blockIdx.y;
    const int tx = threadIdx.x & 31, ty = threadIdx.x >> 5;
#pragma unroll
    for (int i = 0; i < 4; i++)
        tile[ty + i * 8][tx] = (__bf16)W2[(size_t)(kt * 32 + ty + i * 8) * V_ + vt * 32 + tx];
    __syncthreads();
#pragma unroll
    for (int i = 0; i < 4; i++)
        W2t[(size_t)(vt * 32 + ty + i * 8) * D_ + kt * 32 + tx] = tile[tx][ty + i * 8];
}

// ---------------------------------------------------------------------------
// Kernel 3: hidden = tanh(encp + decp + b1) -> bf16. Unchanged.
// ---------------------------------------------------------------------------
__global__ __launch_bounds__(256) void hidden_kernel(
    const float* __restrict__ encp, const float* __restrict__ decp,
    const float* __restrict__ b1, __bf16* __restrict__ H) {
    const unsigned g = blockIdx.x * 256u + threadIdx.x;
    const unsigned row = g / 80u;
    const unsigned hg  = g % 80u;
    const unsigned u   = row % 80u;
    const unsigned bt  = row / 80u;
    const unsigned b   = bt / 160u;

    const float* ep = encp + (size_t)bt * D_ + hg * 8;
    const float* dp = decp + (size_t)(b * 80u + u) * D_ + hg * 8;
    const float* bp = b1 + hg * 8;

    floatx4 e0 = *(const floatx4*)ep,       e1 = *(const floatx4*)(ep + 4);
    floatx4 d0 = *(const floatx4*)dp,       d1 = *(const floatx4*)(dp + 4);
    floatx4 c0 = *(const floatx4*)bp,       c1 = *(const floatx4*)(bp + 4);

    bf16x8 hv;
#pragma unroll
    for (int i = 0; i < 4; i++) hv[i]     = (__bf16)fast_tanh(e0[i] + d0[i] + c0[i]);
#pragma unroll
    for (int i = 0; i < 4; i++) hv[i + 4] = (__bf16)fast_tanh(e1[i] + d1[i] + c1[i]);

    *(bf16x8*)(H + (size_t)g * 8) = hv;
}

// ---------------------------------------------------------------------------
// Kernel 4: C[51200x1024] = H[51200x640] @ W2t[1024x640]^T + b2.
// 256x256 8-phase schedule + FRAGMENT REUSE (this round's change):
// per 4-phase group the wave reads A-half0(8)+B-half0(4) @P0, B-half1(4) @P1,
// A-half1(8) @P2, nothing @P3 — 24 ds_read_b128 per group vs 48 before.
// B-frags stay resident in VGPRs across the group (+32 VGPR, ~215 total).
// Stage/vmcnt schedule identical to the verified round-1 version (reads only
// move earlier, so all WAR margins grow; RAW unchanged).
// ---------------------------------------------------------------------------
#define VM4  asm volatile("s_waitcnt vmcnt(4)" ::: "memory")
#define VM0  asm volatile("s_waitcnt vmcnt(0)" ::: "memory")
#define BAR  __builtin_amdgcn_s_barrier()
#define SCB  __builtin_amdgcn_sched_barrier(0)

#define STG_A(BUF, S, TL) do { \
    g2l16(Hb + (unsigned)((S)*163840 + (TL)*128) + agl,         ldsp + (BUF)*32768 + (S)*16384 + stl); \
    g2l16(Hb + (unsigned)((S)*163840 + (TL)*128 + 10240) + agl, ldsp + (BUF)*32768 + (S)*16384 + stl + 1024); \
  } while (0)
#define STG_B(BUF, S, TL) do { \
    g2l16(Wb + (unsigned)((S)*163840 + (TL)*128) + agl,         ldsp + 65536 + (BUF)*32768 + (S)*16384 + stl); \
    g2l16(Wb + (unsigned)((S)*163840 + (TL)*128 + 10240) + agl, ldsp + 65536 + (BUF)*32768 + (S)*16384 + stl + 1024); \
  } while (0)

// read A-half QM of buffer ABUF into af0/af1 (4 m-frags x 2 K-steps)
#define RD_A(ABUF, QM) do { \
    _Pragma("unroll") for (int ii = 0; ii < 4; ++ii) { \
      af0[ii] = *(const bf16x8*)(ldsp + (ABUF)*32768 + (QM)*16384 + ii*2048 + aRowB + sx0); \
      af1[ii] = *(const bf16x8*)(ldsp + (ABUF)*32768 + (QM)*16384 + ii*2048 + aRowB + sx1); \
    } } while (0)
// read B-half QN of buffer BBUF into BG0/BG1 (2 n-frags x 2 K-steps)
#define RD_B(BG0, BG1, BBUF, QN) do { \
    _Pragma("unroll") for (int jj = 0; jj < 2; ++jj) { \
      BG0[jj] = *(const bf16x8*)(ldsp + 65536 + (BBUF)*32768 + (QN)*16384 + jj*2048 + bRowB + sx0); \
      BG1[jj] = *(const bf16x8*)(ldsp + 65536 + (BBUF)*32768 + (QN)*16384 + jj*2048 + bRowB + sx1); \
    } } while (0)
// 16 MFMAs for quadrant (QM,QN) using current af and the given B-frags
#define MM(QM, QN, BG0, BG1) do { \
    __builtin_amdgcn_s_setprio(1); \
    _Pragma("unroll") for (int ii = 0; ii < 4; ++ii) \
      _Pragma("unroll") for (int jj = 0; jj < 2; ++jj) { \
        acc[(QM)*4+ii][(QN)*2+jj] = __builtin_amdgcn_mfma_f32_16x16x32_bf16(af0[ii], BG0[jj], acc[(QM)*4+ii][(QN)*2+jj], 0, 0, 0); \
        acc[(QM)*4+ii][(QN)*2+jj] = __builtin_amdgcn_mfma_f32_16x16x32_bf16(af1[ii], BG1[jj], acc[(QM)*4+ii][(QN)*2+jj], 0, 0, 0); \
      } \
    __builtin_amdgcn_s_setprio(0); \
  } while (0)

__global__ __launch_bounds__(512, 2) void gemm_kernel(
    const __bf16* __restrict__ H, const __bf16* __restrict__ W2t,
    const float* __restrict__ b2, float* __restrict__ C) {
    __shared__ __align__(128) char lds[131072];   // A: [0,64K), B: [64K,128K)

    // T1: XCD-aware swizzle. 800 blocks, 8 XCDs, 100 contiguous per XCD.
    const int bid = blockIdx.x;
    const int swz = (bid & 7) * 100 + (bid >> 3);
    const int mt = swz >> 2, nt = swz & 3;        // 200 M-tiles x 4 N-tiles
    const int m0 = mt * 256, n0 = nt * 256;

    const int tid = threadIdx.x;
    const int w = tid >> 6, l = tid & 63;
    const int wr = w >> 2, wc = w & 3;            // 2 x 4 wave grid
    const int lrow = l & 15, lk = l >> 4, l7 = l & 7, lhi = l >> 3;

    // staging: global col pre-swizzled so linear LDS dest yields
    // lds[row][slot] = global[row][slot ^ (row&7)]  (row&7 == lhi here).
    const unsigned swzb = (unsigned)(((l & 7) ^ lhi) * 16);
    const unsigned agl  = (unsigned)((w * 16 + lhi) * 1280) + swzb;
    const unsigned stl  = (unsigned)(w * 2048 + l * 16);

    const char* Hb = (const char*)H   + (size_t)m0 * 1280;
    const char* Wb = (const char*)W2t + (size_t)n0 * 1280;
    char* ldsp = (char*)lds;

    // ds_read per-lane constants (read applies the same XOR swizzle)
    const unsigned aRowB = (unsigned)((wr * 64 + lrow) * 128);
    const unsigned bRowB = (unsigned)(wc * 4096 + lrow * 128);
    const unsigned sx0 = (unsigned)(((0 + lk) ^ l7) * 16);
    const unsigned sx1 = (unsigned)(((4 + lk) ^ l7) * 16);

    floatx4 acc[8][4] = {};

    // Prologue: tile0 (4 slices) + tile1 (A0,B0); force tile0, leave 4 in flight.
    STG_A(0, 0, 0); STG_A(0, 1, 0); STG_B(0, 0, 0); STG_B(0, 1, 0);
    STG_A(1, 0, 1); STG_B(1, 0, 1);
    VM4; BAR; SCB;

#pragma unroll 1
    for (int it = 0; it < 5; ++it) {            // 10 K-tiles, 2 per iter
        const int t1 = 2 * it + 1, t2 = 2 * it + 2, t3 = 2 * it + 3;
        const bool pf = (it < 4);               // t2,t3 <= 9
        bf16x8 af0[4], af1[4], bgA0[2], bgA1[2], bgB0[2], bgB1[2];

        // ---- group 0: buf0 (tile 2it) ----
        // P0
        RD_A(0, 0); RD_B(bgA0, bgA1, 0, 0);
        STG_A(1, 1, t1); STG_B(1, 1, t1);
        BAR; SCB; MM(0, 0, bgA0, bgA1); BAR; SCB;
        // P1
        RD_B(bgB0, bgB1, 0, 1);
        BAR; SCB; MM(0, 1, bgB0, bgB1); BAR; SCB;
        // P2
        RD_A(0, 1);
        if (pf) STG_A(0, 0, t2);
        BAR; SCB; MM(1, 0, bgA0, bgA1); BAR; SCB;
        // P3
        if (pf) STG_B(0, 0, t2);
        if (it == 4) { VM0; } else { VM4; }
        BAR; SCB; MM(1, 1, bgB0, bgB1); BAR; SCB;

        // ---- group 1: buf1 (tile 2it+1) ----
        // P4
        RD_A(1, 0); RD_B(bgA0, bgA1, 1, 0);
        if (pf) { STG_A(0, 1, t2); STG_B(0, 1, t2); }
        BAR; SCB; MM(0, 0, bgA0, bgA1); BAR; SCB;
        // P5
        RD_B(bgB0, bgB1, 1, 1);
        BAR; SCB; MM(0, 1, bgB0, bgB1); BAR; SCB;
        // P6
        RD_A(1, 1);
        if (pf) STG_A(1, 0, t3);
        BAR; SCB; MM(1, 0, bgA0, bgA1); BAR; SCB;
        // P7
        if (pf) STG_B(1, 0, t3);
        VM4;
        BAR; SCB; MM(1, 1, bgB0, bgB1); BAR; SCB;
    }

    // Epilogue: C/D layout col = lane&15 (N), row = (lane>>4)*4 + reg (M).
#pragma unroll
    for (int j = 0; j < 4; ++j) {
        const int col = n0 + (j >> 1) * 128 + wc * 32 + (j & 1) * 16 + lrow;
        const float bj = b2[col];
#pragma unroll
        for (int i = 0; i < 8; ++i) {
            const int row = m0 + (i >> 2) * 128 + wr * 64 + (i & 3) * 16 + lk * 4;
            float* Cp = C + (size_t)row * V_ + col;
#pragma unroll
            for (int rg = 0; rg < 4; ++rg)
                Cp[(size_t)rg * V_] = acc[i][j][rg] + bj;
        }
    }
}

// ---------------------------------------------------------------------------
extern "C" void kernel_launch(void* const* d_in, const int* in_sizes, int n_in,
                              void* d_out, int out_size, void* d_ws, size_t ws_size,
                              hipStream_t stream) {
    const float* enc = (const float*)d_in[0];
    const float* dec = (const float*)d_in[1];
    const float* W1  = (const float*)d_in[2];
    const float* b1  = (const float*)d_in[3];
    const float* W2  = (const float*)d_in[4];
    const float* b2  = (const float*)d_in[5];
    float* out = (float*)d_out;

    // Workspace layout (all 16B aligned), total ~69.3 MB:
    char* ws = (char*)d_ws;
    float*  encp = (float*)ws;                                   // 640*640*4
    float*  decp = (float*)(ws + 1638400);                       // 320*640*4
    __bf16* W2t  = (__bf16*)(ws + 1638400 + 819200);             // 1024*640*2
    __bf16* Hbuf = (__bf16*)(ws + 1638400 + 819200 + 1310720);   // 51200*640*2

    proj_kernel<<<dim3(10, 15), 256, 0, stream>>>(enc, dec, W1, encp, decp);
    w2t_kernel<<<dim3(32, 20), 256, 0, stream>>>(W2, W2t);
    hidden_kernel<<<16000, 256, 0, stream>>>(encp, decp, b1, Hbuf);
    gemm_kernel<<<800, 512, 0, stream>>>(Hbuf, W2t, b2, out);
}